// Round 11
// baseline (719.002 us; speedup 1.0000x reference)
//
#include <hip/hip_runtime.h>
#include <stdint.h>

typedef __bf16 bf16_t;
typedef __bf16 bf16x8 __attribute__((ext_vector_type(8)));
typedef __bf16 bf16x4 __attribute__((ext_vector_type(4)));
typedef float f32x4 __attribute__((ext_vector_type(4)));
typedef float f32x16 __attribute__((ext_vector_type(16)));
typedef unsigned int u32;

#define DEVINL static __device__ __forceinline__

constexpr int BB = 4;
constexpr int SEQ = 2048;
constexpr int HID = 1024;
constexpr int NL = 4;
constexpr int MR = BB * SEQ;  // 8192
constexpr float LN_EPS = 1e-5f;

DEVINL f32x4 mfma16(bf16x8 a, bf16x8 b, f32x4 c) {
  return __builtin_amdgcn_mfma_f32_16x16x32_bf16(a, b, c, 0, 0, 0);
}
DEVINL f32x16 mfma32(bf16x8 a, bf16x8 b, f32x16 c) {
  return __builtin_amdgcn_mfma_f32_32x32x16_bf16(a, b, c, 0, 0, 0);
}

// async global->LDS, 16B/lane; LDS dest wave-uniform base + lane*16.
DEVINL void gload_lds16(const bf16_t* g, bf16_t* l) {
  __builtin_amdgcn_global_load_lds(
      (const __attribute__((address_space(1))) u32*)g,
      (__attribute__((address_space(3))) u32*)l, 16, 0, 0);
}

// ---------------------------------------------------------------------------
// QKV GEMM (round-9 best, unchanged): BM=256 BN=128 BK=64, 8 waves 4Mx2N,
// 2x2 of mfma32, 2-phase, counted vmcnt(2), XOR swizzle, gload_lds, z-outer.
// z==2 (V): vT via per-wave LDS transpose.
// ---------------------------------------------------------------------------
__global__ __launch_bounds__(512, 2) void gemm_qkv(
    const bf16_t* __restrict__ xb, const bf16_t* __restrict__ w0,
    const bf16_t* __restrict__ w1, const bf16_t* __restrict__ w2,
    const float* __restrict__ bias0, const float* __restrict__ bias1,
    const float* __restrict__ bias2, bf16_t* __restrict__ o0,
    bf16_t* __restrict__ o1, bf16_t* __restrict__ vT) {
  constexpr int BM = 256, BN = 128, NT = 16;

  __shared__ bf16_t smem[2 * BM * 64 + 2 * BN * 64];  // 96 KB pool
  bf16_t* lA = smem;
  bf16_t* lB = smem + 2 * BM * 64;

  const int nwg = gridDim.x;
  int Lb = blockIdx.x;
  Lb = (Lb & 7) * (nwg >> 3) + (Lb >> 3);
  const int z = Lb >> 8;
  const int rem = Lb & 255;
  const int tm = rem >> 3;
  const int tn = rem & 7;
  const int brow = tm * BM, bcol = tn * BN;

  const bf16_t* B = (z == 0) ? w0 : (z == 1) ? w1 : w2;
  const float* bias = (z == 0) ? bias0 : (z == 1) ? bias1 : bias2;

  const int t = threadIdx.x, wave = t >> 6, lane = t & 63;
  const int wm = wave >> 1, wn = wave & 1;
  const int r31 = lane & 31, kb2 = lane >> 5;
  const int srow = t >> 3;
  const int cbk = (t & 7) ^ (srow & 7);
  const bf16_t* pAs = xb + (size_t)(brow + srow) * HID + cbk * 8;
  const bf16_t* pBs = B + (size_t)(bcol + srow) * HID + cbk * 8;
  bf16_t* lAw = lA + wave * 512;
  bf16_t* lBw = lB + wave * 512;

#define SA(X_, h_)                                                  \
  gload_lds16(pAs + (size_t)((h_)*64) * HID + (X_)*64,              \
              lAw + ((X_)&1) * (BM * 64) + (h_)*4096)
#define SB(X_, h_)                                                  \
  gload_lds16(pBs + (size_t)((h_)*64) * HID + (X_)*64,              \
              lBw + ((X_)&1) * (BN * 64) + (h_)*4096)

  const char* lAc = (const char*)lA;
  const char* lBc = (const char*)lB;
  int sX[4];
#pragma unroll
  for (int ks = 0; ks < 4; ++ks) sX[ks] = (((ks * 2 + kb2) ^ (r31 & 7)) << 4);
  const int rowA0 = wm * 64 + r31;
  const int rowB0 = wn * 64 + r31;

  f32x16 acc00 = {}, acc01 = {}, acc10 = {}, acc11 = {};

  SA(0, 0); SA(0, 1); SA(0, 2); SA(0, 3);
  SB(0, 0); SB(0, 1);
  SB(1, 0); SB(1, 1);
  asm volatile("s_waitcnt vmcnt(2)" ::: "memory");
  __builtin_amdgcn_s_barrier();

  for (int kt = 0; kt < NT; ++kt) {
    const char* aB = lAc + (kt & 1) * (BM * 128);
    const char* bB = lBc + (kt & 1) * (BN * 128);
    bf16x8 bF[2][4], a0[4];
#pragma unroll
    for (int ni = 0; ni < 2; ++ni)
#pragma unroll
      for (int ks = 0; ks < 4; ++ks)
        bF[ni][ks] = *(const bf16x8*)(bB + (rowB0 + ni * 32) * 128 + sX[ks]);
#pragma unroll
    for (int ks = 0; ks < 4; ++ks)
      a0[ks] = *(const bf16x8*)(aB + rowA0 * 128 + sX[ks]);
    if (kt + 1 < NT) { SA(kt + 1, 0); SA(kt + 1, 1); SA(kt + 1, 2); SA(kt + 1, 3); }
    __builtin_amdgcn_s_barrier();
    __builtin_amdgcn_s_setprio(1);
#pragma unroll
    for (int ks = 0; ks < 4; ++ks) {
      acc00 = mfma32(a0[ks], bF[0][ks], acc00);
      acc01 = mfma32(a0[ks], bF[1][ks], acc01);
    }
    __builtin_amdgcn_s_setprio(0);
    __builtin_amdgcn_s_barrier();
    bf16x8 a1[4];
#pragma unroll
    for (int ks = 0; ks < 4; ++ks)
      a1[ks] = *(const bf16x8*)(aB + (rowA0 + 32) * 128 + sX[ks]);
    if (kt + 2 < NT) { SB(kt + 2, 0); SB(kt + 2, 1); }
    __builtin_amdgcn_s_barrier();
    __builtin_amdgcn_s_setprio(1);
#pragma unroll
    for (int ks = 0; ks < 4; ++ks) {
      acc10 = mfma32(a1[ks], bF[0][ks], acc10);
      acc11 = mfma32(a1[ks], bF[1][ks], acc11);
    }
    __builtin_amdgcn_s_setprio(0);
    if (kt < NT - 2)
      asm volatile("s_waitcnt vmcnt(2)" ::: "memory");
    else
      asm volatile("s_waitcnt vmcnt(0)" ::: "memory");
    __builtin_amdgcn_s_barrier();
  }

  if (z < 2) {
    const int crow = brow + wm * 64 + 4 * kb2;
    const int ccol = bcol + wn * 64 + r31;
    bf16_t* outb = (z == 0) ? o0 : o1;
#pragma unroll
    for (int mi = 0; mi < 2; ++mi) {
#pragma unroll
      for (int ni = 0; ni < 2; ++ni) {
        const f32x16 av = (mi == 0) ? (ni == 0 ? acc00 : acc01)
                                    : (ni == 0 ? acc10 : acc11);
        const int col = ccol + ni * 32;
        const float badd = bias[col];
#pragma unroll
        for (int r = 0; r < 16; ++r) {
          const int row = crow + mi * 32 + (r & 3) + 8 * (r >> 2);
          outb[(size_t)row * HID + col] = (bf16_t)(av[r] + badd);
        }
      }
    }
  } else {
    bf16_t* tp = smem + wave * (64 * 72);
#pragma unroll
    for (int mi = 0; mi < 2; ++mi) {
#pragma unroll
      for (int ni = 0; ni < 2; ++ni) {
        const f32x16 av = (mi == 0) ? (ni == 0 ? acc00 : acc01)
                                    : (ni == 0 ? acc10 : acc11);
        const int cl = r31 + ni * 32;
        const float badd = bias[bcol + wn * 64 + cl];
#pragma unroll
        for (int g = 0; g < 4; ++g) {
          const int rl = mi * 32 + 8 * g + 4 * kb2;
          bf16x4 ov;
#pragma unroll
          for (int i = 0; i < 4; ++i) ov[i] = (bf16_t)(av[4 * g + i] + badd);
          *(bf16x4*)(tp + cl * 72 + rl) = ov;
        }
      }
    }
    asm volatile("s_waitcnt lgkmcnt(0)" ::: "memory");
    const int batch = brow >> 11;
    bf16_t* vt = vT + (size_t)batch * HID * SEQ;
    const int c0 = bcol + wn * 64;
    const int s0 = (brow & 2047) + wm * 64;
    const int lr = lane >> 3, lc = (lane & 7) * 8;
#pragma unroll
    for (int p = 0; p < 8; ++p) {
      const int rt = p * 8 + lr;
      const bf16x8 vv = *(const bf16x8*)(tp + rt * 72 + lc);
      *(bf16x8*)(vt + (size_t)(c0 + rt) * SEQ + s0 + lc) = vv;
    }
  }
#undef SA
#undef SB
}

// ---------------------------------------------------------------------------
// QK GEMM (this round's experiment): same 256x128 / 32x32 / 2-phase K-loop
// as gemm_qkv (copied verbatim). Decode: grid 512 = 4b x 8tm x 16tn.
// Epilogue: P = mask ? exp(s/32) : 0 (bf16) + fused rowsum — reduce across
// the 32 r31-lanes (shfl_xor offsets 1..16 stay within each kb2 half-wave),
// one atomicAdd per row per half-wave.
// ---------------------------------------------------------------------------
__global__ __launch_bounds__(512, 2) void gemm_qk32(
    const bf16_t* __restrict__ q, const bf16_t* __restrict__ k,
    const int* __restrict__ maskp, float* __restrict__ rsum,
    bf16_t* __restrict__ scores) {
  constexpr int BM = 256, BN = 128, NT = 16;

  __shared__ bf16_t smem[2 * BM * 64 + 2 * BN * 64];
  bf16_t* lA = smem;
  bf16_t* lB = smem + 2 * BM * 64;

  const int nwg = gridDim.x;
  int Lb = blockIdx.x;
  Lb = (Lb & 7) * (nwg >> 3) + (Lb >> 3);
  const int z = Lb >> 7;           // batch
  const int rem = Lb & 127;
  const int tm = rem >> 4;         // 0..7
  const int tn = rem & 15;         // 0..15
  const int brow = tm * BM, bcol = tn * BN;

  const bf16_t* A = q + (size_t)z * SEQ * HID;
  const bf16_t* B = k + (size_t)z * SEQ * HID;
  bf16_t* outb = scores + (size_t)z * SEQ * SEQ;

  const int t = threadIdx.x, wave = t >> 6, lane = t & 63;
  const int wm = wave >> 1, wn = wave & 1;
  const int r31 = lane & 31, kb2 = lane >> 5;
  const int srow = t >> 3;
  const int cbk = (t & 7) ^ (srow & 7);
  const bf16_t* pAs = A + (size_t)(brow + srow) * HID + cbk * 8;
  const bf16_t* pBs = B + (size_t)(bcol + srow) * HID + cbk * 8;
  bf16_t* lAw = lA + wave * 512;
  bf16_t* lBw = lB + wave * 512;

#define SA(X_, h_)                                                  \
  gload_lds16(pAs + (size_t)((h_)*64) * HID + (X_)*64,              \
              lAw + ((X_)&1) * (BM * 64) + (h_)*4096)
#define SB(X_, h_)                                                  \
  gload_lds16(pBs + (size_t)((h_)*64) * HID + (X_)*64,              \
              lBw + ((X_)&1) * (BN * 64) + (h_)*4096)

  const char* lAc = (const char*)lA;
  const char* lBc = (const char*)lB;
  int sX[4];
#pragma unroll
  for (int ks = 0; ks < 4; ++ks) sX[ks] = (((ks * 2 + kb2) ^ (r31 & 7)) << 4);
  const int rowA0 = wm * 64 + r31;
  const int rowB0 = wn * 64 + r31;

  f32x16 acc00 = {}, acc01 = {}, acc10 = {}, acc11 = {};

  SA(0, 0); SA(0, 1); SA(0, 2); SA(0, 3);
  SB(0, 0); SB(0, 1);
  SB(1, 0); SB(1, 1);
  asm volatile("s_waitcnt vmcnt(2)" ::: "memory");
  __builtin_amdgcn_s_barrier();

  for (int kt = 0; kt < NT; ++kt) {
    const char* aB = lAc + (kt & 1) * (BM * 128);
    const char* bB = lBc + (kt & 1) * (BN * 128);
    bf16x8 bF[2][4], a0[4];
#pragma unroll
    for (int ni = 0; ni < 2; ++ni)
#pragma unroll
      for (int ks = 0; ks < 4; ++ks)
        bF[ni][ks] = *(const bf16x8*)(bB + (rowB0 + ni * 32) * 128 + sX[ks]);
#pragma unroll
    for (int ks = 0; ks < 4; ++ks)
      a0[ks] = *(const bf16x8*)(aB + rowA0 * 128 + sX[ks]);
    if (kt + 1 < NT) { SA(kt + 1, 0); SA(kt + 1, 1); SA(kt + 1, 2); SA(kt + 1, 3); }
    __builtin_amdgcn_s_barrier();
    __builtin_amdgcn_s_setprio(1);
#pragma unroll
    for (int ks = 0; ks < 4; ++ks) {
      acc00 = mfma32(a0[ks], bF[0][ks], acc00);
      acc01 = mfma32(a0[ks], bF[1][ks], acc01);
    }
    __builtin_amdgcn_s_setprio(0);
    __builtin_amdgcn_s_barrier();
    bf16x8 a1[4];
#pragma unroll
    for (int ks = 0; ks < 4; ++ks)
      a1[ks] = *(const bf16x8*)(aB + (rowA0 + 32) * 128 + sX[ks]);
    if (kt + 2 < NT) { SB(kt + 2, 0); SB(kt + 2, 1); }
    __builtin_amdgcn_s_barrier();
    __builtin_amdgcn_s_setprio(1);
#pragma unroll
    for (int ks = 0; ks < 4; ++ks) {
      acc10 = mfma32(a1[ks], bF[0][ks], acc10);
      acc11 = mfma32(a1[ks], bF[1][ks], acc11);
    }
    __builtin_amdgcn_s_setprio(0);
    if (kt < NT - 2)
      asm volatile("s_waitcnt vmcnt(2)" ::: "memory");
    else
      asm volatile("s_waitcnt vmcnt(0)" ::: "memory");
    __builtin_amdgcn_s_barrier();
  }

  // Epilogue: 32x32 C/D layout, P = mask*exp, fused rowsum.
  const int crow = brow + wm * 64 + 4 * kb2;
  const int ccol = bcol + wn * 64 + r31;
  const int* mrow = maskp + (size_t)z * SEQ;
  float* rs = rsum + (size_t)z * SEQ;
  const int mv0 = mrow[ccol];
  const int mv1 = mrow[ccol + 32];
#pragma unroll
  for (int mi = 0; mi < 2; ++mi) {
    const f32x16 a0v = (mi == 0) ? acc00 : acc10;
    const f32x16 a1v = (mi == 0) ? acc01 : acc11;
#pragma unroll
    for (int r = 0; r < 16; ++r) {
      const int row = crow + mi * 32 + (r & 3) + 8 * (r >> 2);
      const float p0 = mv0 ? __expf(a0v[r] * 0.03125f) : 0.f;
      const float p1 = mv1 ? __expf(a1v[r] * 0.03125f) : 0.f;
      outb[(size_t)row * SEQ + ccol] = (bf16_t)p0;
      outb[(size_t)row * SEQ + ccol + 32] = (bf16_t)p1;
      float rp = p0 + p1;
      rp += __shfl_xor(rp, 1, 64);
      rp += __shfl_xor(rp, 2, 64);
      rp += __shfl_xor(rp, 4, 64);
      rp += __shfl_xor(rp, 8, 64);
      rp += __shfl_xor(rp, 16, 64);
      if (r31 == 0) atomicAdd(&rs[row], rp);
    }
  }
#undef SA
#undef SB
}

// ---------------------------------------------------------------------------
// PV GEMM (round-9 measured-best, restored): 256^2 4-phase 16x16, split-K2.
// out = acc / rsum[row] (bf16 partial). Grid 256 = 8tm*4tn*8(z=batch*2+kh).
// ---------------------------------------------------------------------------
__global__ __launch_bounds__(512, 2) void gemm_pv2(
    const bf16_t* __restrict__ scores, const bf16_t* __restrict__ vT,
    const float* __restrict__ rsum, bf16_t* __restrict__ o0,
    bf16_t* __restrict__ o1) {
  constexpr int TM = 8, TN = 4, NT = 16;

  __shared__ bf16_t lA[2 * 16384];
  __shared__ bf16_t lB[2 * 16384];

  const int nwg = gridDim.x;
  int Lb = blockIdx.x;
  Lb = (Lb & 7) * (nwg >> 3) + (Lb >> 3);
  const int z = Lb / (TM * TN);
  const int rem = Lb - z * (TM * TN);
  const int tm = rem / TN;
  const int tn = rem - tm * TN;
  const int brow = tm * 256, bcol = tn * 256;

  const int zb = z >> 1, kh = z & 1;
  const bf16_t* A = scores + (size_t)zb * SEQ * SEQ + kh * 1024;
  const bf16_t* B = vT + (size_t)zb * HID * SEQ + kh * 1024;
  bf16_t* outb = ((kh == 0) ? o0 : o1) + (size_t)zb * SEQ * HID;

  const int t = threadIdx.x, wave = t >> 6, lane = t & 63;
  const int wm = wave >> 2, wn = wave & 3;
  const int fr = lane & 15, kb = lane >> 4;
  const int srow = t >> 3;
  const int cbk = (t & 7) ^ (srow & 7);
  const bf16_t* pAs = A + (size_t)(brow + srow) * SEQ + cbk * 8;
  const bf16_t* pBs = B + (size_t)(bcol + srow) * SEQ + cbk * 8;
  bf16_t* lAw = lA + wave * 512;
  bf16_t* lBw = lB + wave * 512;

#define SA(X_, h_)                                                  \
  gload_lds16(pAs + (size_t)((h_)*64) * SEQ + (X_)*64,              \
              lAw + ((X_)&1) * 16384 + (h_)*4096)
#define SB(X_, h_)                                                  \
  gload_lds16(pBs + (size_t)((h_)*64) * SEQ + (X_)*64,              \
              lBw + ((X_)&1) * 16384 + (h_)*4096)

  const char* lAc = (const char*)lA;
  const char* lBc = (const char*)lB;
  const int cX0 = ((kb ^ (fr & 7)) << 4);
  const int cX1 = cX0 ^ 64;
  const int bRowOff = (wn & 1) * 64;

  f32x4 acc[8][4] = {};

  SA(0, 0); SA(0, 1); SA(0, 2); SA(0, 3);
  SB(0, 0); SB(0, 1); SB(0, 2); SB(0, 3);
  SA(1, 0); SA(1, 2);
  SB(1, 0); SB(1, 1); SB(1, 2); SB(1, 3);
  asm volatile("s_waitcnt vmcnt(6)" ::: "memory");
  __builtin_amdgcn_s_barrier();

  for (int kt = 0; kt < NT; ++kt) {
    const char* aB = lAc + (kt & 1) * 32768 + wm * 16384;
    const char* bB = lBc + (kt & 1) * 32768 + (wn >> 1) * 16384;
    bf16x8 bf_[4][2];
#pragma unroll
    for (int p = 0; p < 4; ++p) {
      if (p == 0) {
#pragma unroll
        for (int n = 0; n < 4; ++n) {
          const int rb = (bRowOff + n * 16 + fr) * 128;
          bf_[n][0] = *(const bf16x8*)(bB + rb + cX0);
          bf_[n][1] = *(const bf16x8*)(bB + rb + cX1);
        }
      }
      const int ra0 = (p * 32 + fr) * 128;
      const int ra1 = (p * 32 + 16 + fr) * 128;
      bf16x8 a00 = *(const bf16x8*)(aB + ra0 + cX0);
      bf16x8 a01 = *(const bf16x8*)(aB + ra0 + cX1);
      bf16x8 a10 = *(const bf16x8*)(aB + ra1 + cX0);
      bf16x8 a11 = *(const bf16x8*)(aB + ra1 + cX1);
      if (p == 0 && kt + 1 < NT) { SA(kt + 1, 1); SA(kt + 1, 3); }
      if (p == 1 && kt + 2 < NT) { SB(kt + 2, 0); SB(kt + 2, 1); }
      if (p == 2 && kt + 2 < NT) { SA(kt + 2, 0); SA(kt + 2, 2); }
      if (p == 3 && kt + 2 < NT) { SB(kt + 2, 2); SB(kt + 2, 3); }
      __builtin_amdgcn_s_barrier();
      __builtin_amdgcn_s_setprio(1);
#pragma unroll
      for (int n = 0; n < 4; ++n) {
        acc[2 * p][n] = mfma16(a00, bf_[n][0], acc[2 * p][n]);
        acc[2 * p][n] = mfma16(a01, bf_[n][1], acc[2 * p][n]);
        acc[2 * p + 1][n] = mfma16(a10, bf_[n][0], acc[2 * p + 1][n]);
        acc[2 * p + 1][n] = mfma16(a11, bf_[n][1], acc[2 * p + 1][n]);
      }
      __builtin_amdgcn_s_setprio(0);
      if (p == 3) {
        if (kt < NT - 3)
          asm volatile("s_waitcnt vmcnt(6)" ::: "memory");
        else
          asm volatile("s_waitcnt vmcnt(0)" ::: "memory");
      }
      __builtin_amdgcn_s_barrier();
    }
  }

  const float* rv = rsum + (size_t)zb * SEQ;
  const int qr = lane >> 4;
  const int crow = brow + wm * 128 + qr * 4;
  const int ccol = bcol + wn * 64 + fr;
#pragma unroll
  for (int m = 0; m < 8; ++m) {
    const int row = crow + m * 16;
#pragma unroll
    for (int j = 0; j < 4; ++j) {
      const float ri = 1.f / rv[row + j];
#pragma unroll
      for (int n = 0; n < 4; ++n) {
        const int col = ccol + n * 16;
        outb[(size_t)(row + j) * HID + col] = (bf16_t)(acc[m][n][j] * ri);
      }
    }
  }
#undef SA
#undef SB
}

// ---------------------------------------------------------------------------
// merged casts: y=0..2 -> Wq/Wk/Wv, y=3 -> x
__global__ __launch_bounds__(256) void cast4(
    const float* __restrict__ s0, const float* __restrict__ s1,
    const float* __restrict__ s2, const float* __restrict__ s3,
    bf16_t* __restrict__ d0, bf16_t* __restrict__ d1,
    bf16_t* __restrict__ d2, bf16_t* __restrict__ d3, long nW4, long nX4) {
  const int y = blockIdx.y;
  const float* in = (y == 0) ? s0 : (y == 1) ? s1 : (y == 2) ? s2 : s3;
  bf16_t* out = (y == 0) ? d0 : (y == 1) ? d1 : (y == 2) ? d2 : d3;
  const long n4 = (y == 3) ? nX4 : nW4;
  const long stride = (long)gridDim.x * blockDim.x;
  for (long i = (long)blockIdx.x * blockDim.x + threadIdx.x; i < n4;
       i += stride) {
    f32x4 x = *(const f32x4*)(in + i * 4);
    bf16x4 o;
#pragma unroll
    for (int j = 0; j < 4; ++j) o[j] = (bf16_t)x[j];
    *(bf16x4*)(out + i * 4) = o;
  }
}

// y = resid + attn0 + attn1 (bf16 partials); LayerNorm(y).
__global__ __launch_bounds__(256) void resid_ln(
    const bf16_t* __restrict__ part0, const bf16_t* __restrict__ part1,
    const float* __restrict__ xinf, const bf16_t* __restrict__ xinb,
    const float* __restrict__ lnw, const float* __restrict__ lnb,
    float* __restrict__ xout, bf16_t* __restrict__ xbout) {
  const int row = blockIdx.x;
  const int t = threadIdx.x;
  const int wave = t >> 6;
  const int lane = t & 63;
  const size_t base = (size_t)row * HID + t * 4;
  const bf16x4 a0 = *(const bf16x4*)(part0 + base);
  const bf16x4 a1 = *(const bf16x4*)(part1 + base);
  f32x4 xv;
  if (xinf != nullptr) {
    xv = *(const f32x4*)(xinf + base);
  } else {
    const bf16x4 xbv = *(const bf16x4*)(xinb + base);
#pragma unroll
    for (int j = 0; j < 4; ++j) xv[j] = (float)xbv[j];
  }
  f32x4 y;
#pragma unroll
  for (int j = 0; j < 4; ++j) y[j] = (float)a0[j] + (float)a1[j] + xv[j];
  float s1 = y[0] + y[1] + y[2] + y[3];
  float s2 = y[0] * y[0] + y[1] * y[1] + y[2] * y[2] + y[3] * y[3];
#pragma unroll
  for (int off = 32; off > 0; off >>= 1) {
    s1 += __shfl_xor(s1, off, 64);
    s2 += __shfl_xor(s2, off, 64);
  }
  __shared__ float red[8];
  if (lane == 0) {
    red[wave] = s1;
    red[4 + wave] = s2;
  }
  __syncthreads();
  s1 = red[0] + red[1] + red[2] + red[3];
  s2 = red[4] + red[5] + red[6] + red[7];
  const float mu = s1 * (1.f / HID);
  const float var = s2 * (1.f / HID) - mu * mu;
  const float rs = rsqrtf(var + LN_EPS);
  const f32x4 wv = *(const f32x4*)(lnw + t * 4);
  const f32x4 bv = *(const f32x4*)(lnb + t * 4);
  f32x4 o;
#pragma unroll
  for (int j = 0; j < 4; ++j) o[j] = wv[j] * ((y[j] - mu) * rs) + bv[j];
  if (xout != nullptr) *(f32x4*)(xout + base) = o;
  if (xbout != nullptr) {
    bf16x4 ob;
#pragma unroll
    for (int j = 0; j < 4; ++j) ob[j] = (bf16_t)o[j];
    *(bf16x4*)(xbout + base) = ob;
  }
}

// ---------------------------------------------------------------------------
extern "C" void kernel_launch(void* const* d_in, const int* in_sizes, int n_in,
                              void* d_out, int out_size, void* d_ws,
                              size_t ws_size, hipStream_t stream) {
  const float* x_in = (const float*)d_in[0];
  const int* mask = (const int*)d_in[1];
  const float* Wq = (const float*)d_in[2];
  const float* bq = (const float*)d_in[3];
  const float* Wk = (const float*)d_in[4];
  const float* bk = (const float*)d_in[5];
  const float* Wv = (const float*)d_in[6];
  const float* bv = (const float*)d_in[7];
  const float* lnw = (const float*)d_in[8];
  const float* lnb = (const float*)d_in[9];
  float* out = (float*)d_out;

  char* ws = (char*)d_ws;
  size_t off = 0;
  auto alloc = [&](size_t bytes) {
    char* p = ws + off;
    off += (bytes + 255) & ~(size_t)255;
    return (void*)p;
  };
  const size_t LHH = (size_t)NL * HID * HID;
  bf16_t* wqb = (bf16_t*)alloc(LHH * 2);
  bf16_t* wkb = (bf16_t*)alloc(LHH * 2);
  bf16_t* wvb = (bf16_t*)alloc(LHH * 2);
  bf16_t* xb = (bf16_t*)alloc((size_t)MR * HID * 2);
  bf16_t* q = (bf16_t*)alloc((size_t)MR * HID * 2);
  bf16_t* k = (bf16_t*)alloc((size_t)MR * HID * 2);
  bf16_t* vT = (bf16_t*)alloc((size_t)MR * HID * 2);
  bf16_t* scores = (bf16_t*)alloc((size_t)BB * SEQ * SEQ * 2);
  bf16_t* attn0 = (bf16_t*)alloc((size_t)MR * HID * 2);
  bf16_t* attn1 = (bf16_t*)alloc((size_t)MR * HID * 2);
  float* rsum = (float*)alloc((size_t)MR * 4);
  if (off > ws_size) return;

  cast4<<<dim3(1024, 4), 256, 0, stream>>>(Wq, Wk, Wv, x_in, wqb, wkb, wvb, xb,
                                           (long)(LHH / 4),
                                           (long)((size_t)MR * HID / 4));

  for (int l = 0; l < NL; ++l) {
    const size_t wo = (size_t)l * HID * HID;
    // QKV: grid 768; V written transposed (LDS xp)
    gemm_qkv<<<768, 512, 0, stream>>>(xb, wqb + wo, wkb + wo, wvb + wo,
                                      bq + (size_t)l * HID,
                                      bk + (size_t)l * HID,
                                      bv + (size_t)l * HID, q, k, vT);
    // rsum = 0, then P = mask*exp(qk^T/32) with fused atomic rowsum
    hipMemsetAsync(rsum, 0, (size_t)MR * 4, stream);
    gemm_qk32<<<512, 512, 0, stream>>>(q, k, mask, rsum, scores);
    // attn partials = (P @ v) / rsum (split-K 2)
    gemm_pv2<<<256, 512, 0, stream>>>(scores, vT, rsum, attn0, attn1);
    // residual + LayerNorm
    const float* xif = (l == 0) ? x_in : nullptr;
    float* xo = (l == NL - 1) ? out : nullptr;
    bf16_t* xbo = (l == NL - 1) ? nullptr : xb;
    resid_ln<<<MR, 256, 0, stream>>>(attn0, attn1, xif, xb,
                                     lnw + (size_t)l * HID,
                                     lnb + (size_t)l * HID, xo, xbo);
  }
}

// Round 12
// 647.975 us; speedup vs baseline: 1.1096x; 1.1096x over previous
//
#include <hip/hip_runtime.h>
#include <stdint.h>

typedef __bf16 bf16_t;
typedef __bf16 bf16x8 __attribute__((ext_vector_type(8)));
typedef __bf16 bf16x4 __attribute__((ext_vector_type(4)));
typedef float f32x4 __attribute__((ext_vector_type(4)));
typedef float f32x16 __attribute__((ext_vector_type(16)));
typedef unsigned int u32;

#define DEVINL static __device__ __forceinline__

constexpr int BB = 4;
constexpr int SEQ = 2048;
constexpr int HID = 1024;
constexpr int NL = 4;
constexpr int MR = BB * SEQ;  // 8192
constexpr float LN_EPS = 1e-5f;

DEVINL f32x4 mfma16(bf16x8 a, bf16x8 b, f32x4 c) {
  return __builtin_amdgcn_mfma_f32_16x16x32_bf16(a, b, c, 0, 0, 0);
}
DEVINL f32x16 mfma32(bf16x8 a, bf16x8 b, f32x16 c) {
  return __builtin_amdgcn_mfma_f32_32x32x16_bf16(a, b, c, 0, 0, 0);
}

// async global->LDS, 16B/lane; LDS dest wave-uniform base + lane*16.
DEVINL void gload_lds16(const bf16_t* g, bf16_t* l) {
  __builtin_amdgcn_global_load_lds(
      (const __attribute__((address_space(1))) u32*)g,
      (__attribute__((address_space(3))) u32*)l, 16, 0, 0);
}

// ---------------------------------------------------------------------------
// QKV GEMM (round-9 measured best): BM=256 BN=128 BK=64, 8 waves 4Mx2N,
// 2x2 of mfma32, 2-phase, counted vmcnt(2), XOR swizzle, gload_lds, z-outer.
// z==2 (V): vT via per-wave LDS transpose.
// NEW (riskless): blocks 0-15 zero rsum[8192] before their K-loop — replaces
// the per-layer hipMemsetAsync (kernel-boundary orders it before gemm_qk).
// ---------------------------------------------------------------------------
__global__ __launch_bounds__(512, 2) void gemm_qkv(
    const bf16_t* __restrict__ xb, const bf16_t* __restrict__ w0,
    const bf16_t* __restrict__ w1, const bf16_t* __restrict__ w2,
    const float* __restrict__ bias0, const float* __restrict__ bias1,
    const float* __restrict__ bias2, bf16_t* __restrict__ o0,
    bf16_t* __restrict__ o1, bf16_t* __restrict__ vT,
    float* __restrict__ rsum) {
  constexpr int BM = 256, BN = 128, NT = 16;

  __shared__ bf16_t smem[2 * BM * 64 + 2 * BN * 64];  // 96 KB pool
  bf16_t* lA = smem;
  bf16_t* lB = smem + 2 * BM * 64;

  if (blockIdx.x < 16) rsum[blockIdx.x * 512 + threadIdx.x] = 0.f;

  const int nwg = gridDim.x;
  int Lb = blockIdx.x;
  Lb = (Lb & 7) * (nwg >> 3) + (Lb >> 3);
  const int z = Lb >> 8;
  const int rem = Lb & 255;
  const int tm = rem >> 3;
  const int tn = rem & 7;
  const int brow = tm * BM, bcol = tn * BN;

  const bf16_t* B = (z == 0) ? w0 : (z == 1) ? w1 : w2;
  const float* bias = (z == 0) ? bias0 : (z == 1) ? bias1 : bias2;

  const int t = threadIdx.x, wave = t >> 6, lane = t & 63;
  const int wm = wave >> 1, wn = wave & 1;
  const int r31 = lane & 31, kb2 = lane >> 5;
  const int srow = t >> 3;
  const int cbk = (t & 7) ^ (srow & 7);
  const bf16_t* pAs = xb + (size_t)(brow + srow) * HID + cbk * 8;
  const bf16_t* pBs = B + (size_t)(bcol + srow) * HID + cbk * 8;
  bf16_t* lAw = lA + wave * 512;
  bf16_t* lBw = lB + wave * 512;

#define SA(X_, h_)                                                  \
  gload_lds16(pAs + (size_t)((h_)*64) * HID + (X_)*64,              \
              lAw + ((X_)&1) * (BM * 64) + (h_)*4096)
#define SB(X_, h_)                                                  \
  gload_lds16(pBs + (size_t)((h_)*64) * HID + (X_)*64,              \
              lBw + ((X_)&1) * (BN * 64) + (h_)*4096)

  const char* lAc = (const char*)lA;
  const char* lBc = (const char*)lB;
  int sX[4];
#pragma unroll
  for (int ks = 0; ks < 4; ++ks) sX[ks] = (((ks * 2 + kb2) ^ (r31 & 7)) << 4);
  const int rowA0 = wm * 64 + r31;
  const int rowB0 = wn * 64 + r31;

  f32x16 acc00 = {}, acc01 = {}, acc10 = {}, acc11 = {};

  SA(0, 0); SA(0, 1); SA(0, 2); SA(0, 3);
  SB(0, 0); SB(0, 1);
  SB(1, 0); SB(1, 1);
  asm volatile("s_waitcnt vmcnt(2)" ::: "memory");
  __builtin_amdgcn_s_barrier();

  for (int kt = 0; kt < NT; ++kt) {
    const char* aB = lAc + (kt & 1) * (BM * 128);
    const char* bB = lBc + (kt & 1) * (BN * 128);
    bf16x8 bF[2][4], a0[4];
#pragma unroll
    for (int ni = 0; ni < 2; ++ni)
#pragma unroll
      for (int ks = 0; ks < 4; ++ks)
        bF[ni][ks] = *(const bf16x8*)(bB + (rowB0 + ni * 32) * 128 + sX[ks]);
#pragma unroll
    for (int ks = 0; ks < 4; ++ks)
      a0[ks] = *(const bf16x8*)(aB + rowA0 * 128 + sX[ks]);
    if (kt + 1 < NT) { SA(kt + 1, 0); SA(kt + 1, 1); SA(kt + 1, 2); SA(kt + 1, 3); }
    __builtin_amdgcn_s_barrier();
    __builtin_amdgcn_s_setprio(1);
#pragma unroll
    for (int ks = 0; ks < 4; ++ks) {
      acc00 = mfma32(a0[ks], bF[0][ks], acc00);
      acc01 = mfma32(a0[ks], bF[1][ks], acc01);
    }
    __builtin_amdgcn_s_setprio(0);
    __builtin_amdgcn_s_barrier();
    bf16x8 a1[4];
#pragma unroll
    for (int ks = 0; ks < 4; ++ks)
      a1[ks] = *(const bf16x8*)(aB + (rowA0 + 32) * 128 + sX[ks]);
    if (kt + 2 < NT) { SB(kt + 2, 0); SB(kt + 2, 1); }
    __builtin_amdgcn_s_barrier();
    __builtin_amdgcn_s_setprio(1);
#pragma unroll
    for (int ks = 0; ks < 4; ++ks) {
      acc10 = mfma32(a1[ks], bF[0][ks], acc10);
      acc11 = mfma32(a1[ks], bF[1][ks], acc11);
    }
    __builtin_amdgcn_s_setprio(0);
    if (kt < NT - 2)
      asm volatile("s_waitcnt vmcnt(2)" ::: "memory");
    else
      asm volatile("s_waitcnt vmcnt(0)" ::: "memory");
    __builtin_amdgcn_s_barrier();
  }

  // C/D 32x32 layout (m74/m101): col = lane&31, row = (r&3)+8*(r>>2)+4*kb2
  if (z < 2) {
    const int crow = brow + wm * 64 + 4 * kb2;
    const int ccol = bcol + wn * 64 + r31;
    bf16_t* outb = (z == 0) ? o0 : o1;
#pragma unroll
    for (int mi = 0; mi < 2; ++mi) {
#pragma unroll
      for (int ni = 0; ni < 2; ++ni) {
        const f32x16 av = (mi == 0) ? (ni == 0 ? acc00 : acc01)
                                    : (ni == 0 ? acc10 : acc11);
        const int col = ccol + ni * 32;
        const float badd = bias[col];
#pragma unroll
        for (int r = 0; r < 16; ++r) {
          const int row = crow + mi * 32 + (r & 3) + 8 * (r >> 2);
          outb[(size_t)row * HID + col] = (bf16_t)(av[r] + badd);
        }
      }
    }
  } else {
    // V -> vT[batch][h][s] via per-wave LDS transpose.
    bf16_t* tp = smem + wave * (64 * 72);  // 64x64 tile, stride 72
#pragma unroll
    for (int mi = 0; mi < 2; ++mi) {
#pragma unroll
      for (int ni = 0; ni < 2; ++ni) {
        const f32x16 av = (mi == 0) ? (ni == 0 ? acc00 : acc01)
                                    : (ni == 0 ? acc10 : acc11);
        const int cl = r31 + ni * 32;
        const float badd = bias[bcol + wn * 64 + cl];
#pragma unroll
        for (int g = 0; g < 4; ++g) {
          const int rl = mi * 32 + 8 * g + 4 * kb2;
          bf16x4 ov;
#pragma unroll
          for (int i = 0; i < 4; ++i) ov[i] = (bf16_t)(av[4 * g + i] + badd);
          *(bf16x4*)(tp + cl * 72 + rl) = ov;
        }
      }
    }
    asm volatile("s_waitcnt lgkmcnt(0)" ::: "memory");  // same-wave WAR/RAW
    const int batch = brow >> 11;
    bf16_t* vt = vT + (size_t)batch * HID * SEQ;
    const int c0 = bcol + wn * 64;
    const int s0 = (brow & 2047) + wm * 64;
    const int lr = lane >> 3, lc = (lane & 7) * 8;
#pragma unroll
    for (int p = 0; p < 8; ++p) {
      const int rt = p * 8 + lr;
      const bf16x8 vv = *(const bf16x8*)(tp + rt * 72 + lc);
      *(bf16x8*)(vt + (size_t)(c0 + rt) * SEQ + s0 + lc) = vv;
    }
  }
#undef SA
#undef SB
}

// ---------------------------------------------------------------------------
// QK GEMM (round-9 measured best): 256^2 4-phase 16x16.
// P = mask ? exp(s/32) : 0 (bf16, unnormalized), fused atomic rowsum.
// Grid 256 = 1 exact CU round.
// ---------------------------------------------------------------------------
__global__ __launch_bounds__(512, 2) void gemm_qk(
    const bf16_t* __restrict__ Ab, const bf16_t* __restrict__ B0,
    const int* __restrict__ maskp, float* __restrict__ rsum,
    bf16_t* __restrict__ o0) {
  constexpr int TM = 8, TN = 8, NT = 16;

  __shared__ bf16_t lA[2 * 16384];
  __shared__ bf16_t lB[2 * 16384];

  const int nwg = gridDim.x;
  int Lb = blockIdx.x;
  Lb = (Lb & 7) * (nwg >> 3) + (Lb >> 3);
  const int z = Lb / (TM * TN);
  const int rem = Lb - z * (TM * TN);
  const int tm = rem / TN;
  const int tn = rem - tm * TN;
  const int brow = tm * 256, bcol = tn * 256;

  const bf16_t* A = Ab + (size_t)z * SEQ * HID;
  const bf16_t* B = B0 + (size_t)z * SEQ * HID;
  bf16_t* outb = o0 + (size_t)z * SEQ * SEQ;

  const int t = threadIdx.x, wave = t >> 6, lane = t & 63;
  const int wm = wave >> 2, wn = wave & 3;
  const int fr = lane & 15, kb = lane >> 4;
  const int srow = t >> 3;
  const int cbk = (t & 7) ^ (srow & 7);
  const bf16_t* pAs = A + (size_t)(brow + srow) * HID + cbk * 8;
  const bf16_t* pBs = B + (size_t)(bcol + srow) * HID + cbk * 8;
  bf16_t* lAw = lA + wave * 512;
  bf16_t* lBw = lB + wave * 512;

#define SA(X_, h_)                                                  \
  gload_lds16(pAs + (size_t)((h_)*64) * HID + (X_)*64,              \
              lAw + ((X_)&1) * 16384 + (h_)*4096)
#define SB(X_, h_)                                                  \
  gload_lds16(pBs + (size_t)((h_)*64) * HID + (X_)*64,              \
              lBw + ((X_)&1) * 16384 + (h_)*4096)

  const char* lAc = (const char*)lA;
  const char* lBc = (const char*)lB;
  const int cX0 = ((kb ^ (fr & 7)) << 4);
  const int cX1 = cX0 ^ 64;
  const int bRowOff = (wn & 1) * 64;

  f32x4 acc[8][4] = {};

  SA(0, 0); SA(0, 1); SA(0, 2); SA(0, 3);
  SB(0, 0); SB(0, 1); SB(0, 2); SB(0, 3);
  SA(1, 0); SA(1, 2);
  SB(1, 0); SB(1, 1); SB(1, 2); SB(1, 3);
  asm volatile("s_waitcnt vmcnt(6)" ::: "memory");
  __builtin_amdgcn_s_barrier();

  for (int kt = 0; kt < NT; ++kt) {
    const char* aB = lAc + (kt & 1) * 32768 + wm * 16384;
    const char* bB = lBc + (kt & 1) * 32768 + (wn >> 1) * 16384;
    bf16x8 bf_[4][2];
#pragma unroll
    for (int p = 0; p < 4; ++p) {
      if (p == 0) {
#pragma unroll
        for (int n = 0; n < 4; ++n) {
          const int rb = (bRowOff + n * 16 + fr) * 128;
          bf_[n][0] = *(const bf16x8*)(bB + rb + cX0);
          bf_[n][1] = *(const bf16x8*)(bB + rb + cX1);
        }
      }
      const int ra0 = (p * 32 + fr) * 128;
      const int ra1 = (p * 32 + 16 + fr) * 128;
      bf16x8 a00 = *(const bf16x8*)(aB + ra0 + cX0);
      bf16x8 a01 = *(const bf16x8*)(aB + ra0 + cX1);
      bf16x8 a10 = *(const bf16x8*)(aB + ra1 + cX0);
      bf16x8 a11 = *(const bf16x8*)(aB + ra1 + cX1);
      if (p == 0 && kt + 1 < NT) { SA(kt + 1, 1); SA(kt + 1, 3); }
      if (p == 1 && kt + 2 < NT) { SB(kt + 2, 0); SB(kt + 2, 1); }
      if (p == 2 && kt + 2 < NT) { SA(kt + 2, 0); SA(kt + 2, 2); }
      if (p == 3 && kt + 2 < NT) { SB(kt + 2, 2); SB(kt + 2, 3); }
      __builtin_amdgcn_s_barrier();
      __builtin_amdgcn_s_setprio(1);
#pragma unroll
      for (int n = 0; n < 4; ++n) {
        acc[2 * p][n] = mfma16(a00, bf_[n][0], acc[2 * p][n]);
        acc[2 * p][n] = mfma16(a01, bf_[n][1], acc[2 * p][n]);
        acc[2 * p + 1][n] = mfma16(a10, bf_[n][0], acc[2 * p + 1][n]);
        acc[2 * p + 1][n] = mfma16(a11, bf_[n][1], acc[2 * p + 1][n]);
      }
      __builtin_amdgcn_s_setprio(0);
      if (p == 3) {
        if (kt < NT - 3)
          asm volatile("s_waitcnt vmcnt(6)" ::: "memory");
        else
          asm volatile("s_waitcnt vmcnt(0)" ::: "memory");
      }
      __builtin_amdgcn_s_barrier();
    }
  }

  const int qr = lane >> 4;
  const int crow = brow + wm * 128 + qr * 4;
  const int ccol = bcol + wn * 64 + fr;
  const int* mrow = maskp + (size_t)z * SEQ;
  float* rs = rsum + (size_t)z * SEQ;
  int mv[4];
#pragma unroll
  for (int n = 0; n < 4; ++n) mv[n] = mrow[ccol + n * 16];
#pragma unroll
  for (int m = 0; m < 8; ++m) {
    const int row = crow + m * 16;
#pragma unroll
    for (int j = 0; j < 4; ++j) {
      float rp = 0.f;
#pragma unroll
      for (int n = 0; n < 4; ++n) {
        const int col = ccol + n * 16;
        const float p = mv[n] ? __expf(acc[m][n][j] * 0.03125f) : 0.f;
        outb[(size_t)(row + j) * SEQ + col] = (bf16_t)p;
        rp += p;
      }
      rp += __shfl_xor(rp, 1, 64);
      rp += __shfl_xor(rp, 2, 64);
      rp += __shfl_xor(rp, 4, 64);
      rp += __shfl_xor(rp, 8, 64);
      if (fr == 0) atomicAdd(&rs[row + j], rp);
    }
  }
#undef SA
#undef SB
}

// ---------------------------------------------------------------------------
// PV GEMM (round-9 measured best): 256^2 4-phase 16x16, split-K2.
// out = acc / rsum[row] (bf16 partial). Grid 256 = 8tm*4tn*8(z=batch*2+kh).
// ---------------------------------------------------------------------------
__global__ __launch_bounds__(512, 2) void gemm_pv2(
    const bf16_t* __restrict__ scores, const bf16_t* __restrict__ vT,
    const float* __restrict__ rsum, bf16_t* __restrict__ o0,
    bf16_t* __restrict__ o1) {
  constexpr int TM = 8, TN = 4, NT = 16;

  __shared__ bf16_t lA[2 * 16384];
  __shared__ bf16_t lB[2 * 16384];

  const int nwg = gridDim.x;
  int Lb = blockIdx.x;
  Lb = (Lb & 7) * (nwg >> 3) + (Lb >> 3);
  const int z = Lb / (TM * TN);
  const int rem = Lb - z * (TM * TN);
  const int tm = rem / TN;
  const int tn = rem - tm * TN;
  const int brow = tm * 256, bcol = tn * 256;

  const int zb = z >> 1, kh = z & 1;
  const bf16_t* A = scores + (size_t)zb * SEQ * SEQ + kh * 1024;
  const bf16_t* B = vT + (size_t)zb * HID * SEQ + kh * 1024;
  bf16_t* outb = ((kh == 0) ? o0 : o1) + (size_t)zb * SEQ * HID;

  const int t = threadIdx.x, wave = t >> 6, lane = t & 63;
  const int wm = wave >> 2, wn = wave & 3;
  const int fr = lane & 15, kb = lane >> 4;
  const int srow = t >> 3;
  const int cbk = (t & 7) ^ (srow & 7);
  const bf16_t* pAs = A + (size_t)(brow + srow) * SEQ + cbk * 8;
  const bf16_t* pBs = B + (size_t)(bcol + srow) * SEQ + cbk * 8;
  bf16_t* lAw = lA + wave * 512;
  bf16_t* lBw = lB + wave * 512;

#define SA(X_, h_)                                                  \
  gload_lds16(pAs + (size_t)((h_)*64) * SEQ + (X_)*64,              \
              lAw + ((X_)&1) * 16384 + (h_)*4096)
#define SB(X_, h_)                                                  \
  gload_lds16(pBs + (size_t)((h_)*64) * SEQ + (X_)*64,              \
              lBw + ((X_)&1) * 16384 + (h_)*4096)

  const char* lAc = (const char*)lA;
  const char* lBc = (const char*)lB;
  const int cX0 = ((kb ^ (fr & 7)) << 4);
  const int cX1 = cX0 ^ 64;
  const int bRowOff = (wn & 1) * 64;

  f32x4 acc[8][4] = {};

  SA(0, 0); SA(0, 1); SA(0, 2); SA(0, 3);
  SB(0, 0); SB(0, 1); SB(0, 2); SB(0, 3);
  SA(1, 0); SA(1, 2);
  SB(1, 0); SB(1, 1); SB(1, 2); SB(1, 3);
  asm volatile("s_waitcnt vmcnt(6)" ::: "memory");
  __builtin_amdgcn_s_barrier();

  for (int kt = 0; kt < NT; ++kt) {
    const char* aB = lAc + (kt & 1) * 32768 + wm * 16384;
    const char* bB = lBc + (kt & 1) * 32768 + (wn >> 1) * 16384;
    bf16x8 bf_[4][2];
#pragma unroll
    for (int p = 0; p < 4; ++p) {
      if (p == 0) {
#pragma unroll
        for (int n = 0; n < 4; ++n) {
          const int rb = (bRowOff + n * 16 + fr) * 128;
          bf_[n][0] = *(const bf16x8*)(bB + rb + cX0);
          bf_[n][1] = *(const bf16x8*)(bB + rb + cX1);
        }
      }
      const int ra0 = (p * 32 + fr) * 128;
      const int ra1 = (p * 32 + 16 + fr) * 128;
      bf16x8 a00 = *(const bf16x8*)(aB + ra0 + cX0);
      bf16x8 a01 = *(const bf16x8*)(aB + ra0 + cX1);
      bf16x8 a10 = *(const bf16x8*)(aB + ra1 + cX0);
      bf16x8 a11 = *(const bf16x8*)(aB + ra1 + cX1);
      if (p == 0 && kt + 1 < NT) { SA(kt + 1, 1); SA(kt + 1, 3); }
      if (p == 1 && kt + 2 < NT) { SB(kt + 2, 0); SB(kt + 2, 1); }
      if (p == 2 && kt + 2 < NT) { SA(kt + 2, 0); SA(kt + 2, 2); }
      if (p == 3 && kt + 2 < NT) { SB(kt + 2, 2); SB(kt + 2, 3); }
      __builtin_amdgcn_s_barrier();
      __builtin_amdgcn_s_setprio(1);
#pragma unroll
      for (int n = 0; n < 4; ++n) {
        acc[2 * p][n] = mfma16(a00, bf_[n][0], acc[2 * p][n]);
        acc[2 * p][n] = mfma16(a01, bf_[n][1], acc[2 * p][n]);
        acc[2 * p + 1][n] = mfma16(a10, bf_[n][0], acc[2 * p + 1][n]);
        acc[2 * p + 1][n] = mfma16(a11, bf_[n][1], acc[2 * p + 1][n]);
      }
      __builtin_amdgcn_s_setprio(0);
      if (p == 3) {
        if (kt < NT - 3)
          asm volatile("s_waitcnt vmcnt(6)" ::: "memory");
        else
          asm volatile("s_waitcnt vmcnt(0)" ::: "memory");
      }
      __builtin_amdgcn_s_barrier();
    }
  }

  const float* rv = rsum + (size_t)zb * SEQ;
  const int qr = lane >> 4;
  const int crow = brow + wm * 128 + qr * 4;
  const int ccol = bcol + wn * 64 + fr;
#pragma unroll
  for (int m = 0; m < 8; ++m) {
    const int row = crow + m * 16;
#pragma unroll
    for (int j = 0; j < 4; ++j) {
      const float ri = 1.f / rv[row + j];
#pragma unroll
      for (int n = 0; n < 4; ++n) {
        const int col = ccol + n * 16;
        outb[(size_t)(row + j) * HID + col] = (bf16_t)(acc[m][n][j] * ri);
      }
    }
  }
#undef SA
#undef SB
}

// ---------------------------------------------------------------------------
// merged casts: y=0..2 -> Wq/Wk/Wv, y=3 -> x
__global__ __launch_bounds__(256) void cast4(
    const float* __restrict__ s0, const float* __restrict__ s1,
    const float* __restrict__ s2, const float* __restrict__ s3,
    bf16_t* __restrict__ d0, bf16_t* __restrict__ d1,
    bf16_t* __restrict__ d2, bf16_t* __restrict__ d3, long nW4, long nX4) {
  const int y = blockIdx.y;
  const float* in = (y == 0) ? s0 : (y == 1) ? s1 : (y == 2) ? s2 : s3;
  bf16_t* out = (y == 0) ? d0 : (y == 1) ? d1 : (y == 2) ? d2 : d3;
  const long n4 = (y == 3) ? nX4 : nW4;
  const long stride = (long)gridDim.x * blockDim.x;
  for (long i = (long)blockIdx.x * blockDim.x + threadIdx.x; i < n4;
       i += stride) {
    f32x4 x = *(const f32x4*)(in + i * 4);
    bf16x4 o;
#pragma unroll
    for (int j = 0; j < 4; ++j) o[j] = (bf16_t)x[j];
    *(bf16x4*)(out + i * 4) = o;
  }
}

// y = resid + attn0 + attn1 (bf16 partials); LayerNorm(y).
__global__ __launch_bounds__(256) void resid_ln(
    const bf16_t* __restrict__ part0, const bf16_t* __restrict__ part1,
    const float* __restrict__ xinf, const bf16_t* __restrict__ xinb,
    const float* __restrict__ lnw, const float* __restrict__ lnb,
    float* __restrict__ xout, bf16_t* __restrict__ xbout) {
  const int row = blockIdx.x;
  const int t = threadIdx.x;
  const int wave = t >> 6;
  const int lane = t & 63;
  const size_t base = (size_t)row * HID + t * 4;
  const bf16x4 a0 = *(const bf16x4*)(part0 + base);
  const bf16x4 a1 = *(const bf16x4*)(part1 + base);
  f32x4 xv;
  if (xinf != nullptr) {
    xv = *(const f32x4*)(xinf + base);
  } else {
    const bf16x4 xbv = *(const bf16x4*)(xinb + base);
#pragma unroll
    for (int j = 0; j < 4; ++j) xv[j] = (float)xbv[j];
  }
  f32x4 y;
#pragma unroll
  for (int j = 0; j < 4; ++j) y[j] = (float)a0[j] + (float)a1[j] + xv[j];
  float s1 = y[0] + y[1] + y[2] + y[3];
  float s2 = y[0] * y[0] + y[1] * y[1] + y[2] * y[2] + y[3] * y[3];
#pragma unroll
  for (int off = 32; off > 0; off >>= 1) {
    s1 += __shfl_xor(s1, off, 64);
    s2 += __shfl_xor(s2, off, 64);
  }
  __shared__ float red[8];
  if (lane == 0) {
    red[wave] = s1;
    red[4 + wave] = s2;
  }
  __syncthreads();
  s1 = red[0] + red[1] + red[2] + red[3];
  s2 = red[4] + red[5] + red[6] + red[7];
  const float mu = s1 * (1.f / HID);
  const float var = s2 * (1.f / HID) - mu * mu;
  const float rs = rsqrtf(var + LN_EPS);
  const f32x4 wv = *(const f32x4*)(lnw + t * 4);
  const f32x4 bv = *(const f32x4*)(lnb + t * 4);
  f32x4 o;
#pragma unroll
  for (int j = 0; j < 4; ++j) o[j] = wv[j] * ((y[j] - mu) * rs) + bv[j];
  if (xout != nullptr) *(f32x4*)(xout + base) = o;
  if (xbout != nullptr) {
    bf16x4 ob;
#pragma unroll
    for (int j = 0; j < 4; ++j) ob[j] = (bf16_t)o[j];
    *(bf16x4*)(xbout + base) = ob;
  }
}

// ---------------------------------------------------------------------------
extern "C" void kernel_launch(void* const* d_in, const int* in_sizes, int n_in,
                              void* d_out, int out_size, void* d_ws,
                              size_t ws_size, hipStream_t stream) {
  const float* x_in = (const float*)d_in[0];
  const int* mask = (const int*)d_in[1];
  const float* Wq = (const float*)d_in[2];
  const float* bq = (const float*)d_in[3];
  const float* Wk = (const float*)d_in[4];
  const float* bk = (const float*)d_in[5];
  const float* Wv = (const float*)d_in[6];
  const float* bv = (const float*)d_in[7];
  const float* lnw = (const float*)d_in[8];
  const float* lnb = (const float*)d_in[9];
  float* out = (float*)d_out;

  char* ws = (char*)d_ws;
  size_t off = 0;
  auto alloc = [&](size_t bytes) {
    char* p = ws + off;
    off += (bytes + 255) & ~(size_t)255;
    return (void*)p;
  };
  const size_t LHH = (size_t)NL * HID * HID;
  bf16_t* wqb = (bf16_t*)alloc(LHH * 2);
  bf16_t* wkb = (bf16_t*)alloc(LHH * 2);
  bf16_t* wvb = (bf16_t*)alloc(LHH * 2);
  bf16_t* xb = (bf16_t*)alloc((size_t)MR * HID * 2);
  bf16_t* q = (bf16_t*)alloc((size_t)MR * HID * 2);
  bf16_t* k = (bf16_t*)alloc((size_t)MR * HID * 2);
  bf16_t* vT = (bf16_t*)alloc((size_t)MR * HID * 2);
  bf16_t* scores = (bf16_t*)alloc((size_t)BB * SEQ * SEQ * 2);
  bf16_t* attn0 = (bf16_t*)alloc((size_t)MR * HID * 2);
  bf16_t* attn1 = (bf16_t*)alloc((size_t)MR * HID * 2);
  float* rsum = (float*)alloc((size_t)MR * 4);
  if (off > ws_size) return;

  cast4<<<dim3(1024, 4), 256, 0, stream>>>(Wq, Wk, Wv, x_in, wqb, wkb, wvb, xb,
                                           (long)(LHH / 4),
                                           (long)((size_t)MR * HID / 4));

  for (int l = 0; l < NL; ++l) {
    const size_t wo = (size_t)l * HID * HID;
    // QKV: grid 768; V written transposed (LDS xp); also zeroes rsum
    gemm_qkv<<<768, 512, 0, stream>>>(xb, wqb + wo, wkb + wo, wvb + wo,
                                      bq + (size_t)l * HID,
                                      bk + (size_t)l * HID,
                                      bv + (size_t)l * HID, q, k, vT, rsum);
    // P = mask*exp(qk^T/32) with fused atomic rowsum
    gemm_qk<<<256, 512, 0, stream>>>(q, k, mask, rsum, scores);
    // attn partials = (P @ v) / rsum (split-K 2)
    gemm_pv2<<<256, 512, 0, stream>>>(scores, vT, rsum, attn0, attn1);
    // residual + LayerNorm
    const float* xif = (l == 0) ? x_in : nullptr;
    float* xo = (l == NL - 1) ? out : nullptr;
    bf16_t* xbo = (l == NL - 1) ? nullptr : xb;
    resid_ln<<<MR, 256, 0, stream>>>(attn0, attn1, xif, xb,
                                     lnw + (size_t)l * HID,
                                     lnb + (size_t)l * HID, xo, xbo);
  }
}